// Round 1
// baseline (752.836 us; speedup 1.0000x reference)
//
#include <hip/hip_runtime.h>

#define DH 256   // feature dim (D == H == 256)

// ---------------------------------------------------------------- setup kernels

__global__ void k_init(float* __restrict__ deg, int* __restrict__ fill, int n) {
    int i = blockIdx.x * blockDim.x + threadIdx.x;
    if (i < n) { deg[i] = 1.0f; fill[i] = 0; }   // self-loop included in deg
}

__global__ void k_deg(const int* __restrict__ dst, float* __restrict__ deg, int e) {
    int i = blockIdx.x * blockDim.x + threadIdx.x;
    if (i < e) atomicAdd(&deg[dst[i]], 1.0f);
}

__global__ void k_dinv(const float* __restrict__ deg, float* __restrict__ dinv, int n) {
    int i = blockIdx.x * blockDim.x + threadIdx.x;
    if (i < n) dinv[i] = rsqrtf(deg[i]);
}

// single-block exclusive scan of (int)deg -> row_ptr[0..n]
__global__ void k_scan(const float* __restrict__ deg, int* __restrict__ row_ptr, int n) {
    __shared__ int sd[1024];
    __shared__ int carry;
    int tid = threadIdx.x;
    if (tid == 0) carry = 0;
    __syncthreads();
    for (int base = 0; base < n; base += 1024) {
        int i = base + tid;
        int v = (i < n) ? (int)deg[i] : 0;
        sd[tid] = v;
        __syncthreads();
        for (int off = 1; off < 1024; off <<= 1) {
            int t = (tid >= off) ? sd[tid - off] : 0;
            __syncthreads();
            sd[tid] += t;
            __syncthreads();
        }
        int excl = sd[tid] - v;
        int c = carry;
        if (i < n) row_ptr[i] = c + excl;
        int tot = sd[1023];
        __syncthreads();
        if (tid == 0) carry = c + tot;
        __syncthreads();
    }
    if (tid == 0) row_ptr[n] = carry;
}

__global__ void k_self(const float* __restrict__ dinv, const int* __restrict__ row_ptr,
                       int* __restrict__ col, float* __restrict__ wgt,
                       int* __restrict__ fill, int n) {
    int i = blockIdx.x * blockDim.x + threadIdx.x;
    if (i < n) {
        int p = row_ptr[i];
        col[p] = i;
        float d = dinv[i];
        wgt[p] = d * d;
        fill[i] = 1;   // self-loop occupies slot 0
    }
}

__global__ void k_csr(const int* __restrict__ src, const int* __restrict__ dst,
                      const float* __restrict__ dinv, const int* __restrict__ row_ptr,
                      int* __restrict__ fill, int* __restrict__ col,
                      float* __restrict__ wgt, int e) {
    int i = blockIdx.x * blockDim.x + threadIdx.x;
    if (i < e) {
        int s0 = src[i], d0 = dst[i];
        int p = row_ptr[d0] + atomicAdd(&fill[d0], 1);
        col[p] = s0;
        wgt[p] = dinv[s0] * dinv[d0];
    }
}

// ---------------------------------------------------------------- f32 GEMM
// C[n,256] = X[n,256] @ W[256,256].  BM=BN=64, BK=16, 256 thr, 4x4 per thread.

#define BM 64
#define BN 64
#define BK 16

__global__ __launch_bounds__(256) void k_gemm(const float* __restrict__ X,
                                              const float* __restrict__ W,
                                              float* __restrict__ C, int n) {
    __shared__ float sA[BK][72];   // K-major, padded: stride 72 floats (288B, 16B-mult)
    __shared__ float sB[BK][BN];

    int tid = threadIdx.x;
    int tx = tid & 15, ty = tid >> 4;
    int rb = blockIdx.x * BM;
    int cb = blockIdx.y * BN;

    int lr = tid >> 2;          // 0..63  : row within X tile
    int lk = (tid & 3) * 4;     // 0,4,8,12: k offset within X tile
    int wk = tid >> 4;          // 0..15  : k row of W tile
    int wn = (tid & 15) * 4;    // col offset of W tile

    float acc[4][4] = {};

    for (int k0 = 0; k0 < DH; k0 += BK) {
        int row = rb + lr; if (row >= n) row = n - 1;
        float4 xa = *(const float4*)&X[(size_t)row * DH + k0 + lk];
        sA[lk + 0][lr] = xa.x;
        sA[lk + 1][lr] = xa.y;
        sA[lk + 2][lr] = xa.z;
        sA[lk + 3][lr] = xa.w;
        float4 wb = *(const float4*)&W[(size_t)(k0 + wk) * DH + cb + wn];
        *(float4*)&sB[wk][wn] = wb;
        __syncthreads();
#pragma unroll
        for (int k = 0; k < BK; k++) {
            float4 a4 = *(const float4*)&sA[k][ty * 4];
            float4 b4 = *(const float4*)&sB[k][tx * 4];
            float av[4] = {a4.x, a4.y, a4.z, a4.w};
            float bv[4] = {b4.x, b4.y, b4.z, b4.w};
#pragma unroll
            for (int i = 0; i < 4; i++)
#pragma unroll
                for (int j = 0; j < 4; j++)
                    acc[i][j] += av[i] * bv[j];
        }
        __syncthreads();
    }

#pragma unroll
    for (int i = 0; i < 4; i++) {
        int row = rb + ty * 4 + i;
        if (row < n) {
            float4 v = make_float4(acc[i][0], acc[i][1], acc[i][2], acc[i][3]);
            *(float4*)&C[(size_t)row * DH + cb + tx * 4] = v;
        }
    }
}

// ---------------------------------------------------------------- aggregation
// out[i,:] = relu( sum_p wgt[p] * A[col[p],:] + bias )   one block per dst node

__global__ __launch_bounds__(256) void k_agg(const float* __restrict__ A,
                                             const int* __restrict__ row_ptr,
                                             const int* __restrict__ col,
                                             const float* __restrict__ wgt,
                                             const float* __restrict__ bias,
                                             float* __restrict__ out, int n) {
    int i = blockIdx.x;
    int f = threadIdx.x;
    int p0 = row_ptr[i], p1 = row_ptr[i + 1];
    float acc = 0.f;
    for (int p = p0; p < p1; p++) {
        int c = col[p];          // uniform across block -> scalar load
        float w = wgt[p];
        acc += w * A[(size_t)c * DH + f];
    }
    acc += bias[f];
    out[(size_t)i * DH + f] = fmaxf(acc, 0.f);
}

// ---------------------------------------------------------------- edge predictor
// s[i] = dot(h[i,:], We)   (one wave per node)

__global__ __launch_bounds__(256) void k_s(const float* __restrict__ h,
                                           const float* __restrict__ We,
                                           float* __restrict__ s, int n) {
    int gid = blockIdx.x * blockDim.x + threadIdx.x;
    int wid = gid >> 6;
    int lane = threadIdx.x & 63;
    if (wid >= n) return;
    float4 hv = *(const float4*)&h[(size_t)wid * DH + lane * 4];
    float4 wv = *(const float4*)&We[lane * 4];
    float d = hv.x * wv.x + hv.y * wv.y + hv.z * wv.z + hv.w * wv.w;
#pragma unroll
    for (int off = 32; off > 0; off >>= 1) d += __shfl_down(d, off);
    if (lane == 0) s[wid] = d;
}

__global__ void k_y(const int* __restrict__ src, const int* __restrict__ dst,
                    const float* __restrict__ s, const float* __restrict__ be,
                    float* __restrict__ y, int e) {
    int i = blockIdx.x * blockDim.x + threadIdx.x;
    if (i < e) y[i] = 0.5f * (s[src[i]] + s[dst[i]]) + be[0];
}

// ---------------------------------------------------------------- launch

extern "C" void kernel_launch(void* const* d_in, const int* in_sizes, int n_in,
                              void* d_out, int out_size, void* d_ws, size_t ws_size,
                              hipStream_t stream) {
    const float* x  = (const float*)d_in[0];
    const int*   ei = (const int*)d_in[1];
    const float* W1 = (const float*)d_in[2];
    const float* b1 = (const float*)d_in[3];
    const float* W2 = (const float*)d_in[4];
    const float* b2 = (const float*)d_in[5];
    const float* We = (const float*)d_in[6];
    const float* be = (const float*)d_in[7];

    int n = in_sizes[0] / DH;
    int e = in_sizes[1] / 2;
    const int* src = ei;
    const int* dst = ei + e;

    float* out_h = (float*)d_out;                   // n*DH
    float* out_y = out_h + (size_t)n * DH;          // e

    char* w = (char*)d_ws;
    float* A      = (float*)w;  w += (size_t)n * DH * 4;
    float* deg    = (float*)w;  w += (size_t)n * 4;
    float* dinv   = (float*)w;  w += (size_t)n * 4;
    int*   row_ptr= (int*)w;    w += (size_t)(n + 1) * 4;
    int*   fill   = (int*)w;    w += (size_t)n * 4;
    int*   col    = (int*)w;    w += (size_t)(e + n) * 4;
    float* wgt    = (float*)w;  w += (size_t)(e + n) * 4;
    float* sbuf   = (float*)w;  w += (size_t)n * 4;

    const int tb = 256;
    k_init<<<(n + tb - 1) / tb, tb, 0, stream>>>(deg, fill, n);
    k_deg<<<(e + tb - 1) / tb, tb, 0, stream>>>(dst, deg, e);
    k_dinv<<<(n + tb - 1) / tb, tb, 0, stream>>>(deg, dinv, n);
    k_scan<<<1, 1024, 0, stream>>>(deg, row_ptr, n);
    k_self<<<(n + tb - 1) / tb, tb, 0, stream>>>(dinv, row_ptr, col, wgt, fill, n);
    k_csr<<<(e + tb - 1) / tb, tb, 0, stream>>>(src, dst, dinv, row_ptr, fill, col, wgt, e);

    dim3 g1((n + BM - 1) / BM, DH / BN);
    k_gemm<<<g1, 256, 0, stream>>>(x, W1, A, n);            // A = x @ W1
    k_agg<<<n, 256, 0, stream>>>(A, row_ptr, col, wgt, b1, out_h, n);  // h1 (temp in d_out)
    k_gemm<<<g1, 256, 0, stream>>>(out_h, W2, A, n);        // A = h1 @ W2
    k_agg<<<n, 256, 0, stream>>>(A, row_ptr, col, wgt, b2, out_h, n);  // final h
    k_s<<<((size_t)n * 64 + 255) / 256, 256, 0, stream>>>(out_h, We, sbuf, n);
    k_y<<<(e + tb - 1) / tb, tb, 0, stream>>>(src, dst, sbuf, be, out_y, e);
}

// Round 2
// 457.580 us; speedup vs baseline: 1.6453x; 1.6453x over previous
//
#include <hip/hip_runtime.h>
#include <hip/hip_fp16.h>

#define DH 256   // feature dim (D == H == 256)

// ---------------------------------------------------------------- setup kernels

__global__ void k_init(float* __restrict__ deg, int* __restrict__ fill, int n) {
    int i = blockIdx.x * blockDim.x + threadIdx.x;
    if (i < n) { deg[i] = 1.0f; fill[i] = 0; }   // self-loop included in deg
}

__global__ void k_deg(const int* __restrict__ dst, float* __restrict__ deg, int e) {
    int i = blockIdx.x * blockDim.x + threadIdx.x;
    if (i < e) atomicAdd(&deg[dst[i]], 1.0f);
}

__global__ void k_dinv(const float* __restrict__ deg, float* __restrict__ dinv, int n) {
    int i = blockIdx.x * blockDim.x + threadIdx.x;
    if (i < n) dinv[i] = rsqrtf(deg[i]);
}

// ---- hierarchical exclusive scan of (int)deg -> row_ptr[0..n] ----
// phase 1: per-block (1024) exclusive scan of chunk, write chunk-local scan + block total
__global__ __launch_bounds__(1024) void k_scan1(const float* __restrict__ deg,
                                                int* __restrict__ row_ptr,
                                                int* __restrict__ part, int n) {
    __shared__ int sd[1024];
    int tid = threadIdx.x;
    int i = blockIdx.x * 1024 + tid;
    int v = (i < n) ? (int)deg[i] : 0;
    sd[tid] = v;
    __syncthreads();
    for (int off = 1; off < 1024; off <<= 1) {
        int t = (tid >= off) ? sd[tid - off] : 0;
        __syncthreads();
        sd[tid] += t;
        __syncthreads();
    }
    if (i < n) row_ptr[i] = sd[tid] - v;       // exclusive, chunk-local
    if (tid == 1023) part[blockIdx.x] = sd[1023];
}

// phase 2: serial scan of block totals (tiny), also writes row_ptr[n]=grand total
__global__ void k_scan2(int* __restrict__ part, int* __restrict__ row_ptr,
                        int nparts, int n) {
    if (threadIdx.x == 0) {
        int run = 0;
        for (int b = 0; b < nparts; b++) {
            int t = part[b];
            part[b] = run;
            run += t;
        }
        row_ptr[n] = run;
    }
}

// phase 3: add block offsets
__global__ __launch_bounds__(1024) void k_scan3(int* __restrict__ row_ptr,
                                                const int* __restrict__ part, int n) {
    int i = blockIdx.x * 1024 + threadIdx.x;
    if (i < n) row_ptr[i] += part[blockIdx.x];
}

__global__ void k_self(const float* __restrict__ dinv, const int* __restrict__ row_ptr,
                       int* __restrict__ col, float* __restrict__ wgt,
                       int* __restrict__ fill, int n) {
    int i = blockIdx.x * blockDim.x + threadIdx.x;
    if (i < n) {
        int p = row_ptr[i];
        col[p] = i;
        float d = dinv[i];
        wgt[p] = d * d;
        fill[i] = 1;   // self-loop occupies slot 0
    }
}

__global__ void k_csr(const int* __restrict__ src, const int* __restrict__ dst,
                      const float* __restrict__ dinv, const int* __restrict__ row_ptr,
                      int* __restrict__ fill, int* __restrict__ col,
                      float* __restrict__ wgt, int e) {
    int i = blockIdx.x * blockDim.x + threadIdx.x;
    if (i < e) {
        int s0 = src[i], d0 = dst[i];
        int p = row_ptr[d0] + atomicAdd(&fill[d0], 1);
        col[p] = s0;
        wgt[p] = dinv[s0] * dinv[d0];
    }
}

// ---------------------------------------------------------------- f32 GEMM -> f16 out
// C[n,256] = X[n,256] @ W[256,256].  BM=BN=64, BK=16, 256 thr, 4x4 per thread.

#define BM 64
#define BN 64
#define BK 16

__global__ __launch_bounds__(256) void k_gemm(const float* __restrict__ X,
                                              const float* __restrict__ W,
                                              __half* __restrict__ C, int n) {
    __shared__ float sA[BK][72];   // K-major, padded: stride 72 floats
    __shared__ float sB[BK][BN];

    int tid = threadIdx.x;
    int tx = tid & 15, ty = tid >> 4;
    int rb = blockIdx.x * BM;
    int cb = blockIdx.y * BN;

    int lr = tid >> 2;          // 0..63  : row within X tile
    int lk = (tid & 3) * 4;     // 0,4,8,12: k offset within X tile
    int wk = tid >> 4;          // 0..15  : k row of W tile
    int wn = (tid & 15) * 4;    // col offset of W tile

    float acc[4][4] = {};

    for (int k0 = 0; k0 < DH; k0 += BK) {
        int row = rb + lr; if (row >= n) row = n - 1;
        float4 xa = *(const float4*)&X[(size_t)row * DH + k0 + lk];
        sA[lk + 0][lr] = xa.x;
        sA[lk + 1][lr] = xa.y;
        sA[lk + 2][lr] = xa.z;
        sA[lk + 3][lr] = xa.w;
        float4 wb = *(const float4*)&W[(size_t)(k0 + wk) * DH + cb + wn];
        *(float4*)&sB[wk][wn] = wb;
        __syncthreads();
#pragma unroll
        for (int k = 0; k < BK; k++) {
            float4 a4 = *(const float4*)&sA[k][ty * 4];
            float4 b4 = *(const float4*)&sB[k][tx * 4];
            float av[4] = {a4.x, a4.y, a4.z, a4.w};
            float bv[4] = {b4.x, b4.y, b4.z, b4.w};
#pragma unroll
            for (int i = 0; i < 4; i++)
#pragma unroll
                for (int j = 0; j < 4; j++)
                    acc[i][j] += av[i] * bv[j];
        }
        __syncthreads();
    }

#pragma unroll
    for (int i = 0; i < 4; i++) {
        int row = rb + ty * 4 + i;
        if (row < n) {
            __half2 h0 = __float22half2_rn(make_float2(acc[i][0], acc[i][1]));
            __half2 h1 = __float22half2_rn(make_float2(acc[i][2], acc[i][3]));
            uint2 u;
            u.x = *(unsigned int*)&h0;
            u.y = *(unsigned int*)&h1;
            *(uint2*)&C[(size_t)row * DH + cb + tx * 4] = u;
        }
    }
}

// ---------------------------------------------------------------- aggregation
// out[i,:] = relu( sum_p wgt[p] * A[col[p],:] + bias )
// one WAVE per dst node (4 nodes / 256-thread block); A is f16, 8B/lane loads.

__global__ __launch_bounds__(256) void k_agg(const __half* __restrict__ A,
                                             const int* __restrict__ row_ptr,
                                             const int* __restrict__ col,
                                             const float* __restrict__ wgt,
                                             const float* __restrict__ bias,
                                             float* __restrict__ out, int n) {
    int node = (blockIdx.x << 2) + (threadIdx.x >> 6);
    int lane = threadIdx.x & 63;
    if (node >= n) return;
    int p0 = row_ptr[node], p1 = row_ptr[node + 1];

    float a0 = 0.f, a1 = 0.f, a2 = 0.f, a3 = 0.f;
    int p = p0;
    for (; p + 1 < p1; p += 2) {
        int   c0 = col[p],     c1 = col[p + 1];
        float w0 = wgt[p],     w1 = wgt[p + 1];
        uint2 u0 = *(const uint2*)(A + (size_t)c0 * DH + lane * 4);
        uint2 u1 = *(const uint2*)(A + (size_t)c1 * DH + lane * 4);
        float2 f00 = __half22float2(*(__half2*)&u0.x);
        float2 f01 = __half22float2(*(__half2*)&u0.y);
        float2 f10 = __half22float2(*(__half2*)&u1.x);
        float2 f11 = __half22float2(*(__half2*)&u1.y);
        a0 += w0 * f00.x + w1 * f10.x;
        a1 += w0 * f00.y + w1 * f10.y;
        a2 += w0 * f01.x + w1 * f11.x;
        a3 += w0 * f01.y + w1 * f11.y;
    }
    if (p < p1) {
        int   c0 = col[p];
        float w0 = wgt[p];
        uint2 u0 = *(const uint2*)(A + (size_t)c0 * DH + lane * 4);
        float2 f00 = __half22float2(*(__half2*)&u0.x);
        float2 f01 = __half22float2(*(__half2*)&u0.y);
        a0 += w0 * f00.x;
        a1 += w0 * f00.y;
        a2 += w0 * f01.x;
        a3 += w0 * f01.y;
    }

    int f = lane * 4;
    float4 b4 = *(const float4*)&bias[f];
    float4 v = make_float4(fmaxf(a0 + b4.x, 0.f), fmaxf(a1 + b4.y, 0.f),
                           fmaxf(a2 + b4.z, 0.f), fmaxf(a3 + b4.w, 0.f));
    *(float4*)&out[(size_t)node * DH + f] = v;
}

// ---------------------------------------------------------------- edge predictor
// s[i] = dot(h[i,:], We)   (one wave per node)

__global__ __launch_bounds__(256) void k_s(const float* __restrict__ h,
                                           const float* __restrict__ We,
                                           float* __restrict__ s, int n) {
    int gid = blockIdx.x * blockDim.x + threadIdx.x;
    int wid = gid >> 6;
    int lane = threadIdx.x & 63;
    if (wid >= n) return;
    float4 hv = *(const float4*)&h[(size_t)wid * DH + lane * 4];
    float4 wv = *(const float4*)&We[lane * 4];
    float d = hv.x * wv.x + hv.y * wv.y + hv.z * wv.z + hv.w * wv.w;
#pragma unroll
    for (int off = 32; off > 0; off >>= 1) d += __shfl_down(d, off);
    if (lane == 0) s[wid] = d;
}

__global__ void k_y(const int* __restrict__ src, const int* __restrict__ dst,
                    const float* __restrict__ s, const float* __restrict__ be,
                    float* __restrict__ y, int e) {
    int i = blockIdx.x * blockDim.x + threadIdx.x;
    if (i < e) y[i] = 0.5f * (s[src[i]] + s[dst[i]]) + be[0];
}

// ---------------------------------------------------------------- launch

extern "C" void kernel_launch(void* const* d_in, const int* in_sizes, int n_in,
                              void* d_out, int out_size, void* d_ws, size_t ws_size,
                              hipStream_t stream) {
    const float* x  = (const float*)d_in[0];
    const int*   ei = (const int*)d_in[1];
    const float* W1 = (const float*)d_in[2];
    const float* b1 = (const float*)d_in[3];
    const float* W2 = (const float*)d_in[4];
    const float* b2 = (const float*)d_in[5];
    const float* We = (const float*)d_in[6];
    const float* be = (const float*)d_in[7];

    int n = in_sizes[0] / DH;
    int e = in_sizes[1] / 2;
    const int* src = ei;
    const int* dst = ei + e;

    float* out_h = (float*)d_out;                   // n*DH
    float* out_y = out_h + (size_t)n * DH;          // e

    char* w = (char*)d_ws;
    __half* A    = (__half*)w;  w += ((size_t)n * DH * 2 + 255) & ~255ull;
    float* deg    = (float*)w;  w += (size_t)n * 4;
    float* dinv   = (float*)w;  w += (size_t)n * 4;
    int*   row_ptr= (int*)w;    w += (size_t)(n + 1) * 4;
    int*   fill   = (int*)w;    w += (size_t)n * 4;
    int*   col    = (int*)w;    w += (size_t)(e + n) * 4;
    float* wgt    = (float*)w;  w += (size_t)(e + n) * 4;
    float* sbuf   = (float*)w;  w += (size_t)n * 4;
    int*   part   = (int*)w;    w += 4096;

    const int tb = 256;
    int nscan = (n + 1023) / 1024;
    k_init<<<(n + tb - 1) / tb, tb, 0, stream>>>(deg, fill, n);
    k_deg<<<(e + tb - 1) / tb, tb, 0, stream>>>(dst, deg, e);
    k_dinv<<<(n + tb - 1) / tb, tb, 0, stream>>>(deg, dinv, n);
    k_scan1<<<nscan, 1024, 0, stream>>>(deg, row_ptr, part, n);
    k_scan2<<<1, 64, 0, stream>>>(part, row_ptr, nscan, n);
    k_scan3<<<nscan, 1024, 0, stream>>>(row_ptr, part, n);
    k_self<<<(n + tb - 1) / tb, tb, 0, stream>>>(dinv, row_ptr, col, wgt, fill, n);
    k_csr<<<(e + tb - 1) / tb, tb, 0, stream>>>(src, dst, dinv, row_ptr, fill, col, wgt, e);

    dim3 g1((n + BM - 1) / BM, DH / BN);
    k_gemm<<<g1, 256, 0, stream>>>(x, W1, A, n);            // A = x @ W1  (f16)
    k_agg<<<(n + 3) / 4, 256, 0, stream>>>(A, row_ptr, col, wgt, b1, out_h, n);  // h1
    k_gemm<<<g1, 256, 0, stream>>>(out_h, W2, A, n);        // A = h1 @ W2 (f16)
    k_agg<<<(n + 3) / 4, 256, 0, stream>>>(A, row_ptr, col, wgt, b2, out_h, n);  // final h
    k_s<<<((size_t)n * 64 + 255) / 256, 256, 0, stream>>>(out_h, We, sbuf, n);
    k_y<<<(e + tb - 1) / tb, tb, 0, stream>>>(src, dst, sbuf, be, out_y, e);
}

// Round 3
// 395.508 us; speedup vs baseline: 1.9035x; 1.1569x over previous
//
#include <hip/hip_runtime.h>
#include <hip/hip_fp16.h>

#define DH 256   // feature dim (D == H == 256)

typedef _Float16 half8 __attribute__((ext_vector_type(8)));
typedef float floatx4 __attribute__((ext_vector_type(4)));

// ---------------------------------------------------------------- setup kernels

__global__ void k_init(float* __restrict__ deg, int* __restrict__ fill, int n) {
    int i = blockIdx.x * blockDim.x + threadIdx.x;
    if (i < n) { deg[i] = 1.0f; fill[i] = 0; }   // self-loop included in deg
}

__global__ void k_deg(const int* __restrict__ dst, float* __restrict__ deg, int e) {
    int i = blockIdx.x * blockDim.x + threadIdx.x;
    if (i < e) atomicAdd(&deg[dst[i]], 1.0f);
}

// ---- hierarchical exclusive scan of (int)deg -> row_ptr[0..n]; also dinv ----
__global__ __launch_bounds__(1024) void k_scan1(const float* __restrict__ deg,
                                                float* __restrict__ dinv,
                                                int* __restrict__ row_ptr,
                                                int* __restrict__ part, int n) {
    __shared__ int sd[1024];
    int tid = threadIdx.x;
    int i = blockIdx.x * 1024 + tid;
    float dv = (i < n) ? deg[i] : 1.f;
    if (i < n) dinv[i] = rsqrtf(dv);
    int v = (i < n) ? (int)dv : 0;
    sd[tid] = v;
    __syncthreads();
    for (int off = 1; off < 1024; off <<= 1) {
        int t = (tid >= off) ? sd[tid - off] : 0;
        __syncthreads();
        sd[tid] += t;
        __syncthreads();
    }
    if (i < n) row_ptr[i] = sd[tid] - v;       // exclusive, chunk-local
    if (tid == 1023) part[blockIdx.x] = sd[1023];
}

__global__ void k_scan2(int* __restrict__ part, int* __restrict__ row_ptr,
                        int nparts, int n) {
    if (threadIdx.x == 0) {
        int run = 0;
        for (int b = 0; b < nparts; b++) {
            int t = part[b];
            part[b] = run;
            run += t;
        }
        row_ptr[n] = run;
    }
}

__global__ __launch_bounds__(1024) void k_scan3(int* __restrict__ row_ptr,
                                                const int* __restrict__ part, int n) {
    int i = blockIdx.x * 1024 + threadIdx.x;
    if (i < n) row_ptr[i] += part[blockIdx.x];
}

__global__ void k_self(const float* __restrict__ dinv, const int* __restrict__ row_ptr,
                       int* __restrict__ col, float* __restrict__ wgt,
                       int* __restrict__ fill, int n) {
    int i = blockIdx.x * blockDim.x + threadIdx.x;
    if (i < n) {
        int p = row_ptr[i];
        col[p] = i;
        float d = dinv[i];
        wgt[p] = d * d;
        fill[i] = 1;   // self-loop occupies slot 0
    }
}

__global__ void k_csr(const int* __restrict__ src, const int* __restrict__ dst,
                      const float* __restrict__ dinv, const int* __restrict__ row_ptr,
                      int* __restrict__ fill, int* __restrict__ col,
                      float* __restrict__ wgt, int e) {
    int i = blockIdx.x * blockDim.x + threadIdx.x;
    if (i < e) {
        int s0 = src[i], d0 = dst[i];
        int p = row_ptr[d0] + atomicAdd(&fill[d0], 1);
        col[p] = s0;
        wgt[p] = dinv[s0] * dinv[d0];
    }
}

// transpose+cast: W[k][n] f32 -> Wt[n][k] f16  (256x256); z selects weight
__global__ __launch_bounds__(256) void k_tw(const float* __restrict__ W1,
                                            _Float16* __restrict__ Wt1,
                                            const float* __restrict__ W2,
                                            _Float16* __restrict__ Wt2) {
    const float* W = blockIdx.z ? W2 : W1;
    _Float16* Wt = blockIdx.z ? Wt2 : Wt1;
    __shared__ float t[32][33];
    int bx = blockIdx.x * 32, by = blockIdx.y * 32;
    int tx = threadIdx.x & 31, ty = threadIdx.x >> 5;  // 32 x 8
#pragma unroll
    for (int r = 0; r < 32; r += 8)
        t[ty + r][tx] = W[(size_t)(by + ty + r) * DH + bx + tx];
    __syncthreads();
#pragma unroll
    for (int r = 0; r < 32; r += 8)
        Wt[(size_t)(bx + ty + r) * DH + by + tx] = (_Float16)t[tx][ty + r];
}

// ---------------------------------------------------------------- MFMA GEMM
// C[m][n] (f16) = A[m][0:256] @ W[0:256][n], via D^T trick:
//   mfma A-operand = Wt rows (n, k), B-operand = A rows (m as cols, k)
//   -> lane holds 4 consecutive n per fragment: packed 8B stores.
// block = 4 waves, wave = 16 rows, no LDS.

template <bool AF32>
__global__ __launch_bounds__(256) void k_gemm_mfma(const void* __restrict__ Av,
                                                   const _Float16* __restrict__ Wt,
                                                   _Float16* __restrict__ C, int n) {
    int tid = threadIdx.x;
    int wave = tid >> 6, lane = tid & 63;
    int lm = lane & 15;        // B-frag col = m within 16-row tile
    int kg = lane >> 4;        // k-group 0..3
    int m = blockIdx.x * 64 + wave * 16 + lm;
    int mc = min(m, n - 1);

    floatx4 acc[16];
#pragma unroll
    for (int j = 0; j < 16; j++) acc[j] = (floatx4){0.f, 0.f, 0.f, 0.f};

    const float*    Af = (const float*)Av;
    const _Float16* Ah = (const _Float16*)Av;

    for (int s = 0; s < 8; s++) {
        int k0 = s * 32 + kg * 8;
        half8 bfrag;
        if (AF32) {
            const float* p = Af + (size_t)mc * DH + k0;
            float4 x0 = *(const float4*)p;
            float4 x1 = *(const float4*)(p + 4);
            bfrag[0] = (_Float16)x0.x; bfrag[1] = (_Float16)x0.y;
            bfrag[2] = (_Float16)x0.z; bfrag[3] = (_Float16)x0.w;
            bfrag[4] = (_Float16)x1.x; bfrag[5] = (_Float16)x1.y;
            bfrag[6] = (_Float16)x1.z; bfrag[7] = (_Float16)x1.w;
        } else {
            bfrag = *(const half8*)(Ah + (size_t)mc * DH + k0);
        }
#pragma unroll
        for (int j = 0; j < 16; j++) {
            half8 afrag = *(const half8*)(Wt + (size_t)(j * 16 + lm) * DH + k0);
            acc[j] = __builtin_amdgcn_mfma_f32_16x16x32_f16(afrag, bfrag, acc[j], 0, 0, 0);
        }
    }

    if (m < n) {
        _Float16* crow = C + (size_t)m * DH + kg * 4;
#pragma unroll
        for (int j = 0; j < 16; j++) {
            __half2 h0 = __float22half2_rn(make_float2(acc[j][0], acc[j][1]));
            __half2 h1 = __float22half2_rn(make_float2(acc[j][2], acc[j][3]));
            uint2 u;
            u.x = *(unsigned int*)&h0;
            u.y = *(unsigned int*)&h1;
            *(uint2*)(crow + j * 16) = u;
        }
    }
}

// ---------------------------------------------------------------- aggregation
// one WAVE per dst node; A is f16, 8B/lane loads.

// variant 1: f16 output (h1, feeds gemm2)
__global__ __launch_bounds__(256) void k_agg_h(const __half* __restrict__ A,
                                               const int* __restrict__ row_ptr,
                                               const int* __restrict__ col,
                                               const float* __restrict__ wgt,
                                               const float* __restrict__ bias,
                                               __half* __restrict__ out, int n) {
    int node = (blockIdx.x << 2) + (threadIdx.x >> 6);
    int lane = threadIdx.x & 63;
    if (node >= n) return;
    int p0 = row_ptr[node], p1 = row_ptr[node + 1];

    float a0 = 0.f, a1 = 0.f, a2 = 0.f, a3 = 0.f;
    int p = p0;
    for (; p + 1 < p1; p += 2) {
        int   c0 = col[p],     c1 = col[p + 1];
        float w0 = wgt[p],     w1 = wgt[p + 1];
        uint2 u0 = *(const uint2*)(A + (size_t)c0 * DH + lane * 4);
        uint2 u1 = *(const uint2*)(A + (size_t)c1 * DH + lane * 4);
        float2 f00 = __half22float2(*(__half2*)&u0.x);
        float2 f01 = __half22float2(*(__half2*)&u0.y);
        float2 f10 = __half22float2(*(__half2*)&u1.x);
        float2 f11 = __half22float2(*(__half2*)&u1.y);
        a0 += w0 * f00.x + w1 * f10.x;
        a1 += w0 * f00.y + w1 * f10.y;
        a2 += w0 * f01.x + w1 * f11.x;
        a3 += w0 * f01.y + w1 * f11.y;
    }
    if (p < p1) {
        int   c0 = col[p];
        float w0 = wgt[p];
        uint2 u0 = *(const uint2*)(A + (size_t)c0 * DH + lane * 4);
        float2 f00 = __half22float2(*(__half2*)&u0.x);
        float2 f01 = __half22float2(*(__half2*)&u0.y);
        a0 += w0 * f00.x;
        a1 += w0 * f00.y;
        a2 += w0 * f01.x;
        a3 += w0 * f01.y;
    }

    int f = lane * 4;
    float4 b4 = *(const float4*)&bias[f];
    __half2 h0 = __float22half2_rn(make_float2(fmaxf(a0 + b4.x, 0.f), fmaxf(a1 + b4.y, 0.f)));
    __half2 h1 = __float22half2_rn(make_float2(fmaxf(a2 + b4.z, 0.f), fmaxf(a3 + b4.w, 0.f)));
    uint2 u;
    u.x = *(unsigned int*)&h0;
    u.y = *(unsigned int*)&h1;
    *(uint2*)(out + (size_t)node * DH + f) = u;
}

// variant 2: f32 output (final h) + fused edge-predictor dot s[node]=h.We
__global__ __launch_bounds__(256) void k_agg_f(const __half* __restrict__ A,
                                               const int* __restrict__ row_ptr,
                                               const int* __restrict__ col,
                                               const float* __restrict__ wgt,
                                               const float* __restrict__ bias,
                                               const float* __restrict__ We,
                                               float* __restrict__ out,
                                               float* __restrict__ s, int n) {
    int node = (blockIdx.x << 2) + (threadIdx.x >> 6);
    int lane = threadIdx.x & 63;
    if (node >= n) return;
    int p0 = row_ptr[node], p1 = row_ptr[node + 1];

    float a0 = 0.f, a1 = 0.f, a2 = 0.f, a3 = 0.f;
    int p = p0;
    for (; p + 1 < p1; p += 2) {
        int   c0 = col[p],     c1 = col[p + 1];
        float w0 = wgt[p],     w1 = wgt[p + 1];
        uint2 u0 = *(const uint2*)(A + (size_t)c0 * DH + lane * 4);
        uint2 u1 = *(const uint2*)(A + (size_t)c1 * DH + lane * 4);
        float2 f00 = __half22float2(*(__half2*)&u0.x);
        float2 f01 = __half22float2(*(__half2*)&u0.y);
        float2 f10 = __half22float2(*(__half2*)&u1.x);
        float2 f11 = __half22float2(*(__half2*)&u1.y);
        a0 += w0 * f00.x + w1 * f10.x;
        a1 += w0 * f00.y + w1 * f10.y;
        a2 += w0 * f01.x + w1 * f11.x;
        a3 += w0 * f01.y + w1 * f11.y;
    }
    if (p < p1) {
        int   c0 = col[p];
        float w0 = wgt[p];
        uint2 u0 = *(const uint2*)(A + (size_t)c0 * DH + lane * 4);
        float2 f00 = __half22float2(*(__half2*)&u0.x);
        float2 f01 = __half22float2(*(__half2*)&u0.y);
        a0 += w0 * f00.x;
        a1 += w0 * f00.y;
        a2 += w0 * f01.x;
        a3 += w0 * f01.y;
    }

    int f = lane * 4;
    float4 b4 = *(const float4*)&bias[f];
    float4 v = make_float4(fmaxf(a0 + b4.x, 0.f), fmaxf(a1 + b4.y, 0.f),
                           fmaxf(a2 + b4.z, 0.f), fmaxf(a3 + b4.w, 0.f));
    *(float4*)&out[(size_t)node * DH + f] = v;

    float4 wv = *(const float4*)&We[f];
    float d = v.x * wv.x + v.y * wv.y + v.z * wv.z + v.w * wv.w;
#pragma unroll
    for (int off = 32; off > 0; off >>= 1) d += __shfl_down(d, off);
    if (lane == 0) s[node] = d;
}

// ---------------------------------------------------------------- edge output

__global__ void k_y(const int* __restrict__ src, const int* __restrict__ dst,
                    const float* __restrict__ s, const float* __restrict__ be,
                    float* __restrict__ y, int e) {
    int i = blockIdx.x * blockDim.x + threadIdx.x;
    if (i < e) y[i] = 0.5f * (s[src[i]] + s[dst[i]]) + be[0];
}

// ---------------------------------------------------------------- launch

extern "C" void kernel_launch(void* const* d_in, const int* in_sizes, int n_in,
                              void* d_out, int out_size, void* d_ws, size_t ws_size,
                              hipStream_t stream) {
    const float* x  = (const float*)d_in[0];
    const int*   ei = (const int*)d_in[1];
    const float* W1 = (const float*)d_in[2];
    const float* b1 = (const float*)d_in[3];
    const float* W2 = (const float*)d_in[4];
    const float* b2 = (const float*)d_in[5];
    const float* We = (const float*)d_in[6];
    const float* be = (const float*)d_in[7];

    int n = in_sizes[0] / DH;
    int e = in_sizes[1] / 2;
    const int* src = ei;
    const int* dst = ei + e;

    float* out_h = (float*)d_out;                   // n*DH
    float* out_y = out_h + (size_t)n * DH;          // e

    char* w = (char*)d_ws;
    _Float16* A   = (_Float16*)w;  w += ((size_t)n * DH * 2 + 255) & ~255ull;
    _Float16* h1  = (_Float16*)w;  w += ((size_t)n * DH * 2 + 255) & ~255ull;
    _Float16* Wt1 = (_Float16*)w;  w += (size_t)DH * DH * 2;
    _Float16* Wt2 = (_Float16*)w;  w += (size_t)DH * DH * 2;
    float* deg    = (float*)w;  w += (size_t)n * 4;
    float* dinv   = (float*)w;  w += (size_t)n * 4;
    int*   row_ptr= (int*)w;    w += (size_t)(n + 1) * 4;
    int*   fill   = (int*)w;    w += (size_t)n * 4;
    int*   col    = (int*)w;    w += (size_t)(e + n) * 4;
    float* wgt    = (float*)w;  w += (size_t)(e + n) * 4;
    float* sbuf   = (float*)w;  w += (size_t)n * 4;
    int*   part   = (int*)w;    w += 4096;

    const int tb = 256;
    int nscan = (n + 1023) / 1024;
    k_init<<<(n + tb - 1) / tb, tb, 0, stream>>>(deg, fill, n);
    k_deg<<<(e + tb - 1) / tb, tb, 0, stream>>>(dst, deg, e);
    k_scan1<<<nscan, 1024, 0, stream>>>(deg, dinv, row_ptr, part, n);
    k_scan2<<<1, 64, 0, stream>>>(part, row_ptr, nscan, n);
    k_scan3<<<nscan, 1024, 0, stream>>>(row_ptr, part, n);
    k_self<<<(n + tb - 1) / tb, tb, 0, stream>>>(dinv, row_ptr, col, wgt, fill, n);
    k_csr<<<(e + tb - 1) / tb, tb, 0, stream>>>(src, dst, dinv, row_ptr, fill, col, wgt, e);
    dim3 gt(8, 8, 2);
    k_tw<<<gt, 256, 0, stream>>>(W1, Wt1, W2, Wt2);

    int gg = (n + 63) / 64;
    k_gemm_mfma<true><<<gg, 256, 0, stream>>>(x, Wt1, A, n);                    // A = x@W1 (f16)
    k_agg_h<<<(n + 3) / 4, 256, 0, stream>>>((const __half*)A, row_ptr, col, wgt, b1,
                                             (__half*)h1, n);                   // h1 (f16)
    k_gemm_mfma<false><<<gg, 256, 0, stream>>>(h1, Wt2, A, n);                  // A = h1@W2 (f16)
    k_agg_f<<<(n + 3) / 4, 256, 0, stream>>>((const __half*)A, row_ptr, col, wgt, b2,
                                             We, out_h, sbuf, n);               // final h + s
    k_y<<<(e + tb - 1) / tb, tb, 0, stream>>>(src, dst, sbuf, be, out_y, e);
}

// Round 4
// 343.451 us; speedup vs baseline: 2.1920x; 1.1516x over previous
//
#include <hip/hip_runtime.h>
#include <hip/hip_fp16.h>

#define DH 256   // feature dim (D == H == 256)

typedef _Float16 half8 __attribute__((ext_vector_type(8)));
typedef float floatx4 __attribute__((ext_vector_type(4)));

// ---------------------------------------------------------------- setup kernels

__global__ void k_init(float* __restrict__ deg, int* __restrict__ fill, int n) {
    int i = blockIdx.x * blockDim.x + threadIdx.x;
    if (i < n) { deg[i] = 1.0f; fill[i] = 0; }   // self-loop included in deg
}

__global__ void k_deg(const int* __restrict__ dst, float* __restrict__ deg, int e) {
    int i = blockIdx.x * blockDim.x + threadIdx.x;
    if (i < e) atomicAdd(&deg[dst[i]], 1.0f);
}

// ---- hierarchical exclusive scan of (int)deg -> row_ptr[0..n]; also dinv ----
__global__ __launch_bounds__(1024) void k_scan1(const float* __restrict__ deg,
                                                float* __restrict__ dinv,
                                                int* __restrict__ row_ptr,
                                                int* __restrict__ part, int n) {
    __shared__ int sd[1024];
    int tid = threadIdx.x;
    int i = blockIdx.x * 1024 + tid;
    float dv = (i < n) ? deg[i] : 1.f;
    if (i < n) dinv[i] = rsqrtf(dv);
    int v = (i < n) ? (int)dv : 0;
    sd[tid] = v;
    __syncthreads();
    for (int off = 1; off < 1024; off <<= 1) {
        int t = (tid >= off) ? sd[tid - off] : 0;
        __syncthreads();
        sd[tid] += t;
        __syncthreads();
    }
    if (i < n) row_ptr[i] = sd[tid] - v;       // exclusive, chunk-local
    if (tid == 1023) part[blockIdx.x] = sd[1023];
}

__global__ void k_scan2(int* __restrict__ part, int* __restrict__ row_ptr,
                        int nparts, int n) {
    if (threadIdx.x == 0) {
        int run = 0;
        for (int b = 0; b < nparts; b++) {
            int t = part[b];
            part[b] = run;
            run += t;
        }
        row_ptr[n] = run;
    }
}

__global__ __launch_bounds__(1024) void k_scan3(int* __restrict__ row_ptr,
                                                const int* __restrict__ part, int n) {
    int i = blockIdx.x * 1024 + threadIdx.x;
    if (i < n) row_ptr[i] += part[blockIdx.x];
}

__global__ void k_self(const float* __restrict__ dinv, const int* __restrict__ row_ptr,
                       int* __restrict__ col, float* __restrict__ wgt,
                       int* __restrict__ fill, int n) {
    int i = blockIdx.x * blockDim.x + threadIdx.x;
    if (i < n) {
        int p = row_ptr[i];
        col[p] = i;
        float d = dinv[i];
        wgt[p] = d * d;
        fill[i] = 1;   // self-loop occupies slot 0
    }
}

__global__ void k_csr(const int* __restrict__ src, const int* __restrict__ dst,
                      const float* __restrict__ dinv, const int* __restrict__ row_ptr,
                      int* __restrict__ fill, int* __restrict__ col,
                      float* __restrict__ wgt, int e) {
    int i = blockIdx.x * blockDim.x + threadIdx.x;
    if (i < e) {
        int s0 = src[i], d0 = dst[i];
        int p = row_ptr[d0] + atomicAdd(&fill[d0], 1);
        col[p] = s0;
        wgt[p] = dinv[s0] * dinv[d0];
    }
}

// transpose+cast: W[k][n] f32 -> Wt[n][k] f16  (256x256); z selects weight
__global__ __launch_bounds__(256) void k_tw(const float* __restrict__ W1,
                                            _Float16* __restrict__ Wt1,
                                            const float* __restrict__ W2,
                                            _Float16* __restrict__ Wt2) {
    const float* W = blockIdx.z ? W2 : W1;
    _Float16* Wt = blockIdx.z ? Wt2 : Wt1;
    __shared__ float t[32][33];
    int bx = blockIdx.x * 32, by = blockIdx.y * 32;
    int tx = threadIdx.x & 31, ty = threadIdx.x >> 5;  // 32 x 8
#pragma unroll
    for (int r = 0; r < 32; r += 8)
        t[ty + r][tx] = W[(size_t)(by + ty + r) * DH + bx + tx];
    __syncthreads();
#pragma unroll
    for (int r = 0; r < 32; r += 8)
        Wt[(size_t)(bx + ty + r) * DH + by + tx] = (_Float16)t[tx][ty + r];
}

// ---------------------------------------------------------------- MFMA GEMM
// C[m][0:256] (f16) = A[m][0:256] @ W, swapped-operand (D=C^T) scheme:
//   A-operand = Wt rows (held in REGISTERS, loaded once), B-operand = X rows.
// Block = 8 waves; wave w owns cols [w*32, w*32+32). Persistent grid-stride
// over 16-row tiles with register double-buffer prefetch of X.

template <bool AF32>
__global__ __launch_bounds__(512, 2) void k_gemm_w(const void* __restrict__ Av,
                                                   const _Float16* __restrict__ Wt,
                                                   _Float16* __restrict__ C,
                                                   int n, int ntiles) {
    int tid = threadIdx.x;
    int wave = tid >> 6, lane = tid & 63;
    int lm = lane & 15;        // row-within-tile (B-frag col)
    int kg = lane >> 4;        // k-group 0..3
    int c0 = wave * 32;        // this wave's output-column base

    // W fragments for this wave's 2 column-tiles, all 8 k-steps: 64 VGPRs.
    half8 wfrag[2][8];
#pragma unroll
    for (int jj = 0; jj < 2; jj++)
#pragma unroll
        for (int s = 0; s < 8; s++)
            wfrag[jj][s] = *(const half8*)(Wt + (size_t)(c0 + jj * 16 + lm) * DH + s * 32 + kg * 8);

    const float*    Af = (const float*)Av;
    const _Float16* Ah = (const _Float16*)Av;
    int stride = gridDim.x;
    int mt = blockIdx.x;
    if (mt >= ntiles) return;

    float4 rf[16];
    half8  rh[8];
    {   // prologue: issue loads for first tile
        int m = min(mt * 16 + lm, n - 1);
        if (AF32) {
            const float* p = Af + (size_t)m * DH + kg * 8;
#pragma unroll
            for (int s = 0; s < 8; s++) {
                rf[2 * s]     = *(const float4*)(p + s * 32);
                rf[2 * s + 1] = *(const float4*)(p + s * 32 + 4);
            }
        } else {
            const _Float16* p = Ah + (size_t)m * DH + kg * 8;
#pragma unroll
            for (int s = 0; s < 8; s++) rh[s] = *(const half8*)(p + s * 32);
        }
    }

    while (mt < ntiles) {
        int mnext = mt + stride;
        float4 nf[16];
        half8  nh[8];
        if (mnext < ntiles) {   // issue next tile's loads (in flight during MFMA)
            int m = min(mnext * 16 + lm, n - 1);
            if (AF32) {
                const float* p = Af + (size_t)m * DH + kg * 8;
#pragma unroll
                for (int s = 0; s < 8; s++) {
                    nf[2 * s]     = *(const float4*)(p + s * 32);
                    nf[2 * s + 1] = *(const float4*)(p + s * 32 + 4);
                }
            } else {
                const _Float16* p = Ah + (size_t)m * DH + kg * 8;
#pragma unroll
                for (int s = 0; s < 8; s++) nh[s] = *(const half8*)(p + s * 32);
            }
        }

        // finalize current B fragments
        half8 bf[8];
        if (AF32) {
#pragma unroll
            for (int s = 0; s < 8; s++) {
                float4 a = rf[2 * s], b = rf[2 * s + 1];
                bf[s][0] = (_Float16)a.x; bf[s][1] = (_Float16)a.y;
                bf[s][2] = (_Float16)a.z; bf[s][3] = (_Float16)a.w;
                bf[s][4] = (_Float16)b.x; bf[s][5] = (_Float16)b.y;
                bf[s][6] = (_Float16)b.z; bf[s][7] = (_Float16)b.w;
            }
        } else {
#pragma unroll
            for (int s = 0; s < 8; s++) bf[s] = rh[s];
        }

        floatx4 acc0 = {0.f, 0.f, 0.f, 0.f};
        floatx4 acc1 = {0.f, 0.f, 0.f, 0.f};
#pragma unroll
        for (int s = 0; s < 8; s++) {
            acc0 = __builtin_amdgcn_mfma_f32_16x16x32_f16(wfrag[0][s], bf[s], acc0, 0, 0, 0);
            acc1 = __builtin_amdgcn_mfma_f32_16x16x32_f16(wfrag[1][s], bf[s], acc1, 0, 0, 0);
        }

        int m = mt * 16 + lm;
        if (m < n) {
            _Float16* crow = C + (size_t)m * DH + c0 + kg * 4;
            __half2 h0 = __float22half2_rn(make_float2(acc0[0], acc0[1]));
            __half2 h1 = __float22half2_rn(make_float2(acc0[2], acc0[3]));
            uint2 u;
            u.x = *(unsigned int*)&h0; u.y = *(unsigned int*)&h1;
            *(uint2*)crow = u;
            h0 = __float22half2_rn(make_float2(acc1[0], acc1[1]));
            h1 = __float22half2_rn(make_float2(acc1[2], acc1[3]));
            u.x = *(unsigned int*)&h0; u.y = *(unsigned int*)&h1;
            *(uint2*)(crow + 16) = u;
        }

        // rotate buffers
        if (AF32) {
#pragma unroll
            for (int s = 0; s < 16; s++) rf[s] = nf[s];
        } else {
#pragma unroll
            for (int s = 0; s < 8; s++) rh[s] = nh[s];
        }
        mt = mnext;
    }
}

// ---------------------------------------------------------------- aggregation
// one WAVE per dst node; A is f16, 8B/lane loads.

// variant 1: f16 output (h1, feeds gemm2)
__global__ __launch_bounds__(256) void k_agg_h(const __half* __restrict__ A,
                                               const int* __restrict__ row_ptr,
                                               const int* __restrict__ col,
                                               const float* __restrict__ wgt,
                                               const float* __restrict__ bias,
                                               __half* __restrict__ out, int n) {
    int node = (blockIdx.x << 2) + (threadIdx.x >> 6);
    int lane = threadIdx.x & 63;
    if (node >= n) return;
    int p0 = row_ptr[node], p1 = row_ptr[node + 1];

    float a0 = 0.f, a1 = 0.f, a2 = 0.f, a3 = 0.f;
    int p = p0;
    for (; p + 1 < p1; p += 2) {
        int   c0 = col[p],     c1 = col[p + 1];
        float w0 = wgt[p],     w1 = wgt[p + 1];
        uint2 u0 = *(const uint2*)(A + (size_t)c0 * DH + lane * 4);
        uint2 u1 = *(const uint2*)(A + (size_t)c1 * DH + lane * 4);
        float2 f00 = __half22float2(*(__half2*)&u0.x);
        float2 f01 = __half22float2(*(__half2*)&u0.y);
        float2 f10 = __half22float2(*(__half2*)&u1.x);
        float2 f11 = __half22float2(*(__half2*)&u1.y);
        a0 += w0 * f00.x + w1 * f10.x;
        a1 += w0 * f00.y + w1 * f10.y;
        a2 += w0 * f01.x + w1 * f11.x;
        a3 += w0 * f01.y + w1 * f11.y;
    }
    if (p < p1) {
        int   c0 = col[p];
        float w0 = wgt[p];
        uint2 u0 = *(const uint2*)(A + (size_t)c0 * DH + lane * 4);
        float2 f00 = __half22float2(*(__half2*)&u0.x);
        float2 f01 = __half22float2(*(__half2*)&u0.y);
        a0 += w0 * f00.x;
        a1 += w0 * f00.y;
        a2 += w0 * f01.x;
        a3 += w0 * f01.y;
    }

    int f = lane * 4;
    float4 b4 = *(const float4*)&bias[f];
    __half2 h0 = __float22half2_rn(make_float2(fmaxf(a0 + b4.x, 0.f), fmaxf(a1 + b4.y, 0.f)));
    __half2 h1 = __float22half2_rn(make_float2(fmaxf(a2 + b4.z, 0.f), fmaxf(a3 + b4.w, 0.f)));
    uint2 u;
    u.x = *(unsigned int*)&h0;
    u.y = *(unsigned int*)&h1;
    *(uint2*)(out + (size_t)node * DH + f) = u;
}

// variant 2: f32 output (final h) + fused edge-predictor dot s[node]=h.We
__global__ __launch_bounds__(256) void k_agg_f(const __half* __restrict__ A,
                                               const int* __restrict__ row_ptr,
                                               const int* __restrict__ col,
                                               const float* __restrict__ wgt,
                                               const float* __restrict__ bias,
                                               const float* __restrict__ We,
                                               float* __restrict__ out,
                                               float* __restrict__ s, int n) {
    int node = (blockIdx.x << 2) + (threadIdx.x >> 6);
    int lane = threadIdx.x & 63;
    if (node >= n) return;
    int p0 = row_ptr[node], p1 = row_ptr[node + 1];

    float a0 = 0.f, a1 = 0.f, a2 = 0.f, a3 = 0.f;
    int p = p0;
    for (; p + 1 < p1; p += 2) {
        int   c0 = col[p],     c1 = col[p + 1];
        float w0 = wgt[p],     w1 = wgt[p + 1];
        uint2 u0 = *(const uint2*)(A + (size_t)c0 * DH + lane * 4);
        uint2 u1 = *(const uint2*)(A + (size_t)c1 * DH + lane * 4);
        float2 f00 = __half22float2(*(__half2*)&u0.x);
        float2 f01 = __half22float2(*(__half2*)&u0.y);
        float2 f10 = __half22float2(*(__half2*)&u1.x);
        float2 f11 = __half22float2(*(__half2*)&u1.y);
        a0 += w0 * f00.x + w1 * f10.x;
        a1 += w0 * f00.y + w1 * f10.y;
        a2 += w0 * f01.x + w1 * f11.x;
        a3 += w0 * f01.y + w1 * f11.y;
    }
    if (p < p1) {
        int   c0 = col[p];
        float w0 = wgt[p];
        uint2 u0 = *(const uint2*)(A + (size_t)c0 * DH + lane * 4);
        float2 f00 = __half22float2(*(__half2*)&u0.x);
        float2 f01 = __half22float2(*(__half2*)&u0.y);
        a0 += w0 * f00.x;
        a1 += w0 * f00.y;
        a2 += w0 * f01.x;
        a3 += w0 * f01.y;
    }

    int f = lane * 4;
    float4 b4 = *(const float4*)&bias[f];
    float4 v = make_float4(fmaxf(a0 + b4.x, 0.f), fmaxf(a1 + b4.y, 0.f),
                           fmaxf(a2 + b4.z, 0.f), fmaxf(a3 + b4.w, 0.f));
    *(float4*)&out[(size_t)node * DH + f] = v;

    float4 wv = *(const float4*)&We[f];
    float d = v.x * wv.x + v.y * wv.y + v.z * wv.z + v.w * wv.w;
#pragma unroll
    for (int off = 32; off > 0; off >>= 1) d += __shfl_down(d, off);
    if (lane == 0) s[node] = d;
}

// ---------------------------------------------------------------- edge output

__global__ void k_y(const int* __restrict__ src, const int* __restrict__ dst,
                    const float* __restrict__ s, const float* __restrict__ be,
                    float* __restrict__ y, int e) {
    int i = blockIdx.x * blockDim.x + threadIdx.x;
    if (i < e) y[i] = 0.5f * (s[src[i]] + s[dst[i]]) + be[0];
}

// ---------------------------------------------------------------- launch

extern "C" void kernel_launch(void* const* d_in, const int* in_sizes, int n_in,
                              void* d_out, int out_size, void* d_ws, size_t ws_size,
                              hipStream_t stream) {
    const float* x  = (const float*)d_in[0];
    const int*   ei = (const int*)d_in[1];
    const float* W1 = (const float*)d_in[2];
    const float* b1 = (const float*)d_in[3];
    const float* W2 = (const float*)d_in[4];
    const float* b2 = (const float*)d_in[5];
    const float* We = (const float*)d_in[6];
    const float* be = (const float*)d_in[7];

    int n = in_sizes[0] / DH;
    int e = in_sizes[1] / 2;
    const int* src = ei;
    const int* dst = ei + e;

    float* out_h = (float*)d_out;                   // n*DH
    float* out_y = out_h + (size_t)n * DH;          // e

    char* w = (char*)d_ws;
    _Float16* A   = (_Float16*)w;  w += ((size_t)n * DH * 2 + 255) & ~255ull;
    _Float16* h1  = (_Float16*)w;  w += ((size_t)n * DH * 2 + 255) & ~255ull;
    _Float16* Wt1 = (_Float16*)w;  w += (size_t)DH * DH * 2;
    _Float16* Wt2 = (_Float16*)w;  w += (size_t)DH * DH * 2;
    float* deg    = (float*)w;  w += (size_t)n * 4;
    float* dinv   = (float*)w;  w += (size_t)n * 4;
    int*   row_ptr= (int*)w;    w += (size_t)(n + 1) * 4;
    int*   fill   = (int*)w;    w += (size_t)n * 4;
    int*   col    = (int*)w;    w += (size_t)(e + n) * 4;
    float* wgt    = (float*)w;  w += (size_t)(e + n) * 4;
    float* sbuf   = (float*)w;  w += (size_t)n * 4;
    int*   part   = (int*)w;    w += 4096;

    const int tb = 256;
    int nscan = (n + 1023) / 1024;
    k_init<<<(n + tb - 1) / tb, tb, 0, stream>>>(deg, fill, n);
    k_deg<<<(e + tb - 1) / tb, tb, 0, stream>>>(dst, deg, e);
    k_scan1<<<nscan, 1024, 0, stream>>>(deg, dinv, row_ptr, part, n);
    k_scan2<<<1, 64, 0, stream>>>(part, row_ptr, nscan, n);
    k_scan3<<<nscan, 1024, 0, stream>>>(row_ptr, part, n);
    k_self<<<(n + tb - 1) / tb, tb, 0, stream>>>(dinv, row_ptr, col, wgt, fill, n);
    k_csr<<<(e + tb - 1) / tb, tb, 0, stream>>>(src, dst, dinv, row_ptr, fill, col, wgt, e);
    dim3 gt(8, 8, 2);
    k_tw<<<gt, 256, 0, stream>>>(W1, Wt1, W2, Wt2);

    int ntiles = (n + 15) / 16;
    k_gemm_w<true><<<256, 512, 0, stream>>>(x, Wt1, A, n, ntiles);              // A = x@W1 (f16)
    k_agg_h<<<(n + 3) / 4, 256, 0, stream>>>((const __half*)A, row_ptr, col, wgt, b1,
                                             (__half*)h1, n);                   // h1 (f16)
    k_gemm_w<false><<<256, 512, 0, stream>>>(h1, Wt2, A, n, ntiles);            // A = h1@W2 (f16)
    k_agg_f<<<(n + 3) / 4, 256, 0, stream>>>((const __half*)A, row_ptr, col, wgt, b2,
                                             We, out_h, sbuf, n);               // final h + s
    k_y<<<(e + tb - 1) / tb, tb, 0, stream>>>(src, dst, sbuf, be, out_y, e);
}

// Round 5
// 328.698 us; speedup vs baseline: 2.2904x; 1.0449x over previous
//
#include <hip/hip_runtime.h>
#include <hip/hip_fp16.h>

#define DH 256   // feature dim (D == H == 256)

typedef _Float16 half8 __attribute__((ext_vector_type(8)));
typedef float floatx4 __attribute__((ext_vector_type(4)));

// ---------------------------------------------------------------- setup kernels

__global__ void k_init(float* __restrict__ deg, int* __restrict__ fill, int n) {
    int i = blockIdx.x * blockDim.x + threadIdx.x;
    if (i < n) { deg[i] = 1.0f; fill[i] = 0; }   // self-loop included in deg
}

__global__ void k_deg(const int* __restrict__ dst, float* __restrict__ deg, int e) {
    int i = blockIdx.x * blockDim.x + threadIdx.x;
    if (i < e) atomicAdd(&deg[dst[i]], 1.0f);
}

// ---- hierarchical exclusive scan of (int)deg -> row_ptr[0..n]; also dinv ----
__global__ __launch_bounds__(1024) void k_scan1(const float* __restrict__ deg,
                                                float* __restrict__ dinv,
                                                int* __restrict__ row_ptr,
                                                int* __restrict__ part, int n) {
    __shared__ int sd[1024];
    int tid = threadIdx.x;
    int i = blockIdx.x * 1024 + tid;
    float dv = (i < n) ? deg[i] : 1.f;
    if (i < n) dinv[i] = rsqrtf(dv);
    int v = (i < n) ? (int)dv : 0;
    sd[tid] = v;
    __syncthreads();
    for (int off = 1; off < 1024; off <<= 1) {
        int t = (tid >= off) ? sd[tid - off] : 0;
        __syncthreads();
        sd[tid] += t;
        __syncthreads();
    }
    if (i < n) row_ptr[i] = sd[tid] - v;       // exclusive, chunk-local
    if (tid == 1023) part[blockIdx.x] = sd[1023];
}

__global__ void k_scan2(int* __restrict__ part, int* __restrict__ row_ptr,
                        int nparts, int n) {
    if (threadIdx.x == 0) {
        int run = 0;
        for (int b = 0; b < nparts; b++) {
            int t = part[b];
            part[b] = run;
            run += t;
        }
        row_ptr[n] = run;
    }
}

// phase 3: add block offsets; also write self-loop CSR entry (fused k_self)
__global__ __launch_bounds__(1024) void k_scan3(int* __restrict__ row_ptr,
                                                const int* __restrict__ part,
                                                const float* __restrict__ dinv,
                                                int* __restrict__ col,
                                                float* __restrict__ wgt,
                                                int* __restrict__ fill, int n) {
    int i = blockIdx.x * 1024 + threadIdx.x;
    if (i < n) {
        int rp = row_ptr[i] + part[blockIdx.x];
        row_ptr[i] = rp;
        col[rp] = i;
        float d = dinv[i];
        wgt[rp] = d * d;
        fill[i] = 1;   // self-loop occupies slot 0
    }
}

__global__ void k_csr(const int* __restrict__ src, const int* __restrict__ dst,
                      const float* __restrict__ dinv, const int* __restrict__ row_ptr,
                      int* __restrict__ fill, int* __restrict__ col,
                      float* __restrict__ wgt, int e) {
    int i = blockIdx.x * blockDim.x + threadIdx.x;
    if (i < e) {
        int s0 = src[i], d0 = dst[i];
        int p = row_ptr[d0] + atomicAdd(&fill[d0], 1);
        col[p] = s0;
        wgt[p] = dinv[s0] * dinv[d0];
    }
}

// transpose+cast: W[k][n] f32 -> Wt[n][k] f16  (256x256); z selects weight
__global__ __launch_bounds__(256) void k_tw(const float* __restrict__ W1,
                                            _Float16* __restrict__ Wt1,
                                            const float* __restrict__ W2,
                                            _Float16* __restrict__ Wt2) {
    const float* W = blockIdx.z ? W2 : W1;
    _Float16* Wt = blockIdx.z ? Wt2 : Wt1;
    __shared__ float t[32][33];
    int bx = blockIdx.x * 32, by = blockIdx.y * 32;
    int tx = threadIdx.x & 31, ty = threadIdx.x >> 5;  // 32 x 8
#pragma unroll
    for (int r = 0; r < 32; r += 8)
        t[ty + r][tx] = W[(size_t)(by + ty + r) * DH + bx + tx];
    __syncthreads();
#pragma unroll
    for (int r = 0; r < 32; r += 8)
        Wt[(size_t)(bx + ty + r) * DH + by + tx] = (_Float16)t[tx][ty + r];
}

// ---------------------------------------------------------------- MFMA GEMM
// (same as R3: W in registers, persistent blocks, reg-double-buffered X)

template <bool AF32>
__global__ __launch_bounds__(512, 2) void k_gemm_w(const void* __restrict__ Av,
                                                   const _Float16* __restrict__ Wt,
                                                   _Float16* __restrict__ C,
                                                   int n, int ntiles) {
    int tid = threadIdx.x;
    int wave = tid >> 6, lane = tid & 63;
    int lm = lane & 15;
    int kg = lane >> 4;
    int c0 = wave * 32;

    half8 wfrag[2][8];
#pragma unroll
    for (int jj = 0; jj < 2; jj++)
#pragma unroll
        for (int s = 0; s < 8; s++)
            wfrag[jj][s] = *(const half8*)(Wt + (size_t)(c0 + jj * 16 + lm) * DH + s * 32 + kg * 8);

    const float*    Af = (const float*)Av;
    const _Float16* Ah = (const _Float16*)Av;
    int stride = gridDim.x;
    int mt = blockIdx.x;
    if (mt >= ntiles) return;

    float4 rf[16];
    half8  rh[8];
    {
        int m = min(mt * 16 + lm, n - 1);
        if (AF32) {
            const float* p = Af + (size_t)m * DH + kg * 8;
#pragma unroll
            for (int s = 0; s < 8; s++) {
                rf[2 * s]     = *(const float4*)(p + s * 32);
                rf[2 * s + 1] = *(const float4*)(p + s * 32 + 4);
            }
        } else {
            const _Float16* p = Ah + (size_t)m * DH + kg * 8;
#pragma unroll
            for (int s = 0; s < 8; s++) rh[s] = *(const half8*)(p + s * 32);
        }
    }

    while (mt < ntiles) {
        int mnext = mt + stride;
        float4 nf[16];
        half8  nh[8];
        if (mnext < ntiles) {
            int m = min(mnext * 16 + lm, n - 1);
            if (AF32) {
                const float* p = Af + (size_t)m * DH + kg * 8;
#pragma unroll
                for (int s = 0; s < 8; s++) {
                    nf[2 * s]     = *(const float4*)(p + s * 32);
                    nf[2 * s + 1] = *(const float4*)(p + s * 32 + 4);
                }
            } else {
                const _Float16* p = Ah + (size_t)m * DH + kg * 8;
#pragma unroll
                for (int s = 0; s < 8; s++) nh[s] = *(const half8*)(p + s * 32);
            }
        }

        half8 bf[8];
        if (AF32) {
#pragma unroll
            for (int s = 0; s < 8; s++) {
                float4 a = rf[2 * s], b = rf[2 * s + 1];
                bf[s][0] = (_Float16)a.x; bf[s][1] = (_Float16)a.y;
                bf[s][2] = (_Float16)a.z; bf[s][3] = (_Float16)a.w;
                bf[s][4] = (_Float16)b.x; bf[s][5] = (_Float16)b.y;
                bf[s][6] = (_Float16)b.z; bf[s][7] = (_Float16)b.w;
            }
        } else {
#pragma unroll
            for (int s = 0; s < 8; s++) bf[s] = rh[s];
        }

        floatx4 acc0 = {0.f, 0.f, 0.f, 0.f};
        floatx4 acc1 = {0.f, 0.f, 0.f, 0.f};
#pragma unroll
        for (int s = 0; s < 8; s++) {
            acc0 = __builtin_amdgcn_mfma_f32_16x16x32_f16(wfrag[0][s], bf[s], acc0, 0, 0, 0);
            acc1 = __builtin_amdgcn_mfma_f32_16x16x32_f16(wfrag[1][s], bf[s], acc1, 0, 0, 0);
        }

        int m = mt * 16 + lm;
        if (m < n) {
            _Float16* crow = C + (size_t)m * DH + c0 + kg * 4;
            __half2 h0 = __float22half2_rn(make_float2(acc0[0], acc0[1]));
            __half2 h1 = __float22half2_rn(make_float2(acc0[2], acc0[3]));
            uint2 u;
            u.x = *(unsigned int*)&h0; u.y = *(unsigned int*)&h1;
            *(uint2*)crow = u;
            h0 = __float22half2_rn(make_float2(acc1[0], acc1[1]));
            h1 = __float22half2_rn(make_float2(acc1[2], acc1[3]));
            u.x = *(unsigned int*)&h0; u.y = *(unsigned int*)&h1;
            *(uint2*)(crow + 16) = u;
        }

        if (AF32) {
#pragma unroll
            for (int s = 0; s < 16; s++) rf[s] = nf[s];
        } else {
#pragma unroll
            for (int s = 0; s < 8; s++) rh[s] = nh[s];
        }
        mt = mnext;
    }
}

// ---------------------------------------------------------------- aggregation
// one WAVE per dst node; A is f16, 8B/lane; 4-deep load pipeline.

#define AGG_BODY                                                                \
    int node = (blockIdx.x << 2) + (threadIdx.x >> 6);                          \
    int lane = threadIdx.x & 63;                                                \
    if (node >= n) return;                                                      \
    int p0 = row_ptr[node], p1 = row_ptr[node + 1];                             \
    float a0 = 0.f, a1 = 0.f, a2 = 0.f, a3 = 0.f;                               \
    const __half* Al = A + lane * 4;                                            \
    int p = p0;                                                                 \
    for (; p + 3 < p1; p += 4) {                                                \
        int   c0 = col[p],     c1 = col[p + 1];                                 \
        int   c2 = col[p + 2], c3 = col[p + 3];                                 \
        uint2 u0 = *(const uint2*)(Al + (size_t)c0 * DH);                       \
        uint2 u1 = *(const uint2*)(Al + (size_t)c1 * DH);                       \
        uint2 u2 = *(const uint2*)(Al + (size_t)c2 * DH);                       \
        uint2 u3 = *(const uint2*)(Al + (size_t)c3 * DH);                       \
        float w0 = wgt[p],     w1 = wgt[p + 1];                                 \
        float w2 = wgt[p + 2], w3 = wgt[p + 3];                                 \
        float2 f0a = __half22float2(*(__half2*)&u0.x);                          \
        float2 f0b = __half22float2(*(__half2*)&u0.y);                          \
        float2 f1a = __half22float2(*(__half2*)&u1.x);                          \
        float2 f1b = __half22float2(*(__half2*)&u1.y);                          \
        float2 f2a = __half22float2(*(__half2*)&u2.x);                          \
        float2 f2b = __half22float2(*(__half2*)&u2.y);                          \
        float2 f3a = __half22float2(*(__half2*)&u3.x);                          \
        float2 f3b = __half22float2(*(__half2*)&u3.y);                          \
        a0 += w0 * f0a.x + w1 * f1a.x + w2 * f2a.x + w3 * f3a.x;                \
        a1 += w0 * f0a.y + w1 * f1a.y + w2 * f2a.y + w3 * f3a.y;                \
        a2 += w0 * f0b.x + w1 * f1b.x + w2 * f2b.x + w3 * f3b.x;                \
        a3 += w0 * f0b.y + w1 * f1b.y + w2 * f2b.y + w3 * f3b.y;                \
    }                                                                           \
    if (p + 1 < p1) {                                                           \
        int   c0 = col[p], c1 = col[p + 1];                                     \
        uint2 u0 = *(const uint2*)(Al + (size_t)c0 * DH);                       \
        uint2 u1 = *(const uint2*)(Al + (size_t)c1 * DH);                       \
        float w0 = wgt[p], w1 = wgt[p + 1];                                     \
        float2 f0a = __half22float2(*(__half2*)&u0.x);                          \
        float2 f0b = __half22float2(*(__half2*)&u0.y);                          \
        float2 f1a = __half22float2(*(__half2*)&u1.x);                          \
        float2 f1b = __half22float2(*(__half2*)&u1.y);                          \
        a0 += w0 * f0a.x + w1 * f1a.x;                                          \
        a1 += w0 * f0a.y + w1 * f1a.y;                                          \
        a2 += w0 * f0b.x + w1 * f1b.x;                                          \
        a3 += w0 * f0b.y + w1 * f1b.y;                                          \
        p += 2;                                                                 \
    }                                                                           \
    if (p < p1) {                                                               \
        int   c0 = col[p];                                                      \
        uint2 u0 = *(const uint2*)(Al + (size_t)c0 * DH);                       \
        float w0 = wgt[p];                                                      \
        float2 f0a = __half22float2(*(__half2*)&u0.x);                          \
        float2 f0b = __half22float2(*(__half2*)&u0.y);                          \
        a0 += w0 * f0a.x;                                                       \
        a1 += w0 * f0a.y;                                                       \
        a2 += w0 * f0b.x;                                                       \
        a3 += w0 * f0b.y;                                                       \
    }

// variant 1: f16 output (h1, feeds gemm2)
__global__ __launch_bounds__(256) void k_agg_h(const __half* __restrict__ A,
                                               const int* __restrict__ row_ptr,
                                               const int* __restrict__ col,
                                               const float* __restrict__ wgt,
                                               const float* __restrict__ bias,
                                               __half* __restrict__ out, int n) {
    AGG_BODY
    int f = lane * 4;
    float4 b4 = *(const float4*)&bias[f];
    __half2 h0 = __float22half2_rn(make_float2(fmaxf(a0 + b4.x, 0.f), fmaxf(a1 + b4.y, 0.f)));
    __half2 h1 = __float22half2_rn(make_float2(fmaxf(a2 + b4.z, 0.f), fmaxf(a3 + b4.w, 0.f)));
    uint2 u;
    u.x = *(unsigned int*)&h0;
    u.y = *(unsigned int*)&h1;
    *(uint2*)(out + (size_t)node * DH + f) = u;
}

// variant 2: f32 output (final h) + fused edge-predictor dot s[node]=h.We
__global__ __launch_bounds__(256) void k_agg_f(const __half* __restrict__ A,
                                               const int* __restrict__ row_ptr,
                                               const int* __restrict__ col,
                                               const float* __restrict__ wgt,
                                               const float* __restrict__ bias,
                                               const float* __restrict__ We,
                                               float* __restrict__ out,
                                               float* __restrict__ s, int n) {
    AGG_BODY
    int f = lane * 4;
    float4 b4 = *(const float4*)&bias[f];
    float4 v = make_float4(fmaxf(a0 + b4.x, 0.f), fmaxf(a1 + b4.y, 0.f),
                           fmaxf(a2 + b4.z, 0.f), fmaxf(a3 + b4.w, 0.f));
    *(float4*)&out[(size_t)node * DH + f] = v;

    float4 wv = *(const float4*)&We[f];
    float d = v.x * wv.x + v.y * wv.y + v.z * wv.z + v.w * wv.w;
#pragma unroll
    for (int off = 32; off > 0; off >>= 1) d += __shfl_down(d, off);
    if (lane == 0) s[node] = d;
}

// ---------------------------------------------------------------- edge output

__global__ void k_y(const int* __restrict__ src, const int* __restrict__ dst,
                    const float* __restrict__ s, const float* __restrict__ be,
                    float* __restrict__ y, int e) {
    int i = blockIdx.x * blockDim.x + threadIdx.x;
    if (i < e) y[i] = 0.5f * (s[src[i]] + s[dst[i]]) + be[0];
}

// ---------------------------------------------------------------- launch

extern "C" void kernel_launch(void* const* d_in, const int* in_sizes, int n_in,
                              void* d_out, int out_size, void* d_ws, size_t ws_size,
                              hipStream_t stream) {
    const float* x  = (const float*)d_in[0];
    const int*   ei = (const int*)d_in[1];
    const float* W1 = (const float*)d_in[2];
    const float* b1 = (const float*)d_in[3];
    const float* W2 = (const float*)d_in[4];
    const float* b2 = (const float*)d_in[5];
    const float* We = (const float*)d_in[6];
    const float* be = (const float*)d_in[7];

    int n = in_sizes[0] / DH;
    int e = in_sizes[1] / 2;
    const int* src = ei;
    const int* dst = ei + e;

    float* out_h = (float*)d_out;                   // n*DH
    float* out_y = out_h + (size_t)n * DH;          // e

    char* w = (char*)d_ws;
    _Float16* A   = (_Float16*)w;  w += ((size_t)n * DH * 2 + 255) & ~255ull;
    _Float16* h1  = (_Float16*)w;  w += ((size_t)n * DH * 2 + 255) & ~255ull;
    _Float16* Wt1 = (_Float16*)w;  w += (size_t)DH * DH * 2;
    _Float16* Wt2 = (_Float16*)w;  w += (size_t)DH * DH * 2;
    float* deg    = (float*)w;  w += (size_t)n * 4;
    float* dinv   = (float*)w;  w += (size_t)n * 4;
    int*   row_ptr= (int*)w;    w += (size_t)(n + 1) * 4;
    int*   fill   = (int*)w;    w += (size_t)n * 4;
    int*   col    = (int*)w;    w += (size_t)(e + n) * 4;
    float* wgt    = (float*)w;  w += (size_t)(e + n) * 4;
    float* sbuf   = (float*)w;  w += (size_t)n * 4;
    int*   part   = (int*)w;    w += 4096;

    const int tb = 256;
    int nscan = (n + 1023) / 1024;
    k_init<<<(n + tb - 1) / tb, tb, 0, stream>>>(deg, fill, n);
    k_deg<<<(e + tb - 1) / tb, tb, 0, stream>>>(dst, deg, e);
    k_scan1<<<nscan, 1024, 0, stream>>>(deg, dinv, row_ptr, part, n);
    k_scan2<<<1, 64, 0, stream>>>(part, row_ptr, nscan, n);
    k_scan3<<<nscan, 1024, 0, stream>>>(row_ptr, part, dinv, col, wgt, fill, n);
    k_csr<<<(e + tb - 1) / tb, tb, 0, stream>>>(src, dst, dinv, row_ptr, fill, col, wgt, e);
    dim3 gt(8, 8, 2);
    k_tw<<<gt, 256, 0, stream>>>(W1, Wt1, W2, Wt2);

    int ntiles = (n + 15) / 16;
    k_gemm_w<true><<<256, 512, 0, stream>>>(x, Wt1, A, n, ntiles);              // A = x@W1 (f16)
    k_agg_h<<<(n + 3) / 4, 256, 0, stream>>>((const __half*)A, row_ptr, col, wgt, b1,
                                             (__half*)h1, n);                   // h1 (f16)
    k_gemm_w<false><<<256, 512, 0, stream>>>(h1, Wt2, A, n, ntiles);            // A = h1@W2 (f16)
    k_agg_f<<<(n + 3) / 4, 256, 0, stream>>>((const __half*)A, row_ptr, col, wgt, b2,
                                             We, out_h, sbuf, n);               // final h + s
    k_y<<<(e + tb - 1) / tb, tb, 0, stream>>>(src, dst, sbuf, be, out_y, e);
}

// Round 6
// 310.124 us; speedup vs baseline: 2.4275x; 1.0599x over previous
//
#include <hip/hip_runtime.h>
#include <hip/hip_fp16.h>

#define DH 256   // feature dim (D == H == 256)

typedef _Float16 half8 __attribute__((ext_vector_type(8)));
typedef float floatx4 __attribute__((ext_vector_type(4)));

// ---------------------------------------------------------------- setup kernels

__global__ void k_init(float* __restrict__ deg, int* __restrict__ fill, int n) {
    int i = blockIdx.x * blockDim.x + threadIdx.x;
    if (i < n) { deg[i] = 1.0f; fill[i] = 0; }   // self-loop included in deg
}

__global__ void k_deg(const int* __restrict__ dst, float* __restrict__ deg, int e) {
    int i = blockIdx.x * blockDim.x + threadIdx.x;
    if (i < e) atomicAdd(&deg[dst[i]], 1.0f);
}

// ---- hierarchical exclusive scan of (int)deg -> row_ptr[0..n]; also dinv ----
__global__ __launch_bounds__(1024) void k_scan1(const float* __restrict__ deg,
                                                float* __restrict__ dinv,
                                                int* __restrict__ row_ptr,
                                                int* __restrict__ part, int n) {
    __shared__ int sd[1024];
    int tid = threadIdx.x;
    int i = blockIdx.x * 1024 + tid;
    float dv = (i < n) ? deg[i] : 1.f;
    if (i < n) dinv[i] = rsqrtf(dv);
    int v = (i < n) ? (int)dv : 0;
    sd[tid] = v;
    __syncthreads();
    for (int off = 1; off < 1024; off <<= 1) {
        int t = (tid >= off) ? sd[tid - off] : 0;
        __syncthreads();
        sd[tid] += t;
        __syncthreads();
    }
    if (i < n) row_ptr[i] = sd[tid] - v;       // exclusive, chunk-local
    if (tid == 1023) part[blockIdx.x] = sd[1023];
}

__global__ void k_scan2(int* __restrict__ part, int* __restrict__ row_ptr,
                        int nparts, int n) {
    if (threadIdx.x == 0) {
        int run = 0;
        for (int b = 0; b < nparts; b++) {
            int t = part[b];
            part[b] = run;
            run += t;
        }
        row_ptr[n] = run;
    }
}

// phase 3: add block offsets; also write self-loop CSR entry (fused k_self)
__global__ __launch_bounds__(1024) void k_scan3(int* __restrict__ row_ptr,
                                                const int* __restrict__ part,
                                                const float* __restrict__ dinv,
                                                int* __restrict__ col,
                                                float* __restrict__ wgt,
                                                int* __restrict__ fill, int n) {
    int i = blockIdx.x * 1024 + threadIdx.x;
    if (i < n) {
        int rp = row_ptr[i] + part[blockIdx.x];
        row_ptr[i] = rp;
        col[rp] = i;
        float d = dinv[i];
        wgt[rp] = d * d;
        fill[i] = 1;   // self-loop occupies slot 0
    }
}

__global__ void k_csr(const int* __restrict__ src, const int* __restrict__ dst,
                      const float* __restrict__ dinv, const int* __restrict__ row_ptr,
                      int* __restrict__ fill, int* __restrict__ col,
                      float* __restrict__ wgt, int e) {
    int i = blockIdx.x * blockDim.x + threadIdx.x;
    if (i < e) {
        int s0 = src[i], d0 = dst[i];
        int p = row_ptr[d0] + atomicAdd(&fill[d0], 1);
        col[p] = s0;
        wgt[p] = dinv[s0] * dinv[d0];
    }
}

// transpose+cast: W[k][n] f32 -> Wt[n][k] f16  (256x256); z selects weight
__global__ __launch_bounds__(256) void k_tw(const float* __restrict__ W1,
                                            _Float16* __restrict__ Wt1,
                                            const float* __restrict__ W2,
                                            _Float16* __restrict__ Wt2) {
    const float* W = blockIdx.z ? W2 : W1;
    _Float16* Wt = blockIdx.z ? Wt2 : Wt1;
    __shared__ float t[32][33];
    int bx = blockIdx.x * 32, by = blockIdx.y * 32;
    int tx = threadIdx.x & 31, ty = threadIdx.x >> 5;  // 32 x 8
#pragma unroll
    for (int r = 0; r < 32; r += 8)
        t[ty + r][tx] = W[(size_t)(by + ty + r) * DH + bx + tx];
    __syncthreads();
#pragma unroll
    for (int r = 0; r < 32; r += 8)
        Wt[(size_t)(bx + ty + r) * DH + by + tx] = (_Float16)t[tx][ty + r];
}

// cast X f32 -> f16 (8 elems / thread / iter)
__global__ __launch_bounds__(256) void k_xh(const float* __restrict__ x,
                                            _Float16* __restrict__ xh, int elems8) {
    int i = blockIdx.x * blockDim.x + threadIdx.x;
    int stride = gridDim.x * blockDim.x;
    for (int j = i; j < elems8; j += stride) {
        const float* p = x + (size_t)j * 8;
        float4 a = *(const float4*)p;
        float4 b = *(const float4*)(p + 4);
        half8 h;
        h[0] = (_Float16)a.x; h[1] = (_Float16)a.y;
        h[2] = (_Float16)a.z; h[3] = (_Float16)a.w;
        h[4] = (_Float16)b.x; h[5] = (_Float16)b.y;
        h[6] = (_Float16)b.z; h[7] = (_Float16)b.w;
        *(half8*)(xh + (size_t)j * 8) = h;
    }
}

// ---------------------------------------------------------------- MFMA GEMM
// C[m][0:256] (f16) = A[m][0:256] @ W.  W in registers; 4-buffer / 3-ahead
// register pipeline over 16-row tiles; contiguous tile chunk per block.

__device__ __forceinline__ void gload(half8 (&buf)[8], int t, int tend, int lm, int kg,
                                      const _Float16* __restrict__ Xh, int n) {
    if (t < tend) {
        int m = min(t * 16 + lm, n - 1);
        const _Float16* p = Xh + (size_t)m * DH + kg * 8;
#pragma unroll
        for (int s = 0; s < 8; s++) buf[s] = *(const half8*)(p + s * 32);
    }
}

__device__ __forceinline__ void gcomp(half8 (&buf)[8], const half8 (&wf)[2][8],
                                      int t, int tend, int lm, int kg, int c0,
                                      _Float16* __restrict__ C, int n) {
    if (t >= tend) return;
    floatx4 acc0 = {0.f, 0.f, 0.f, 0.f};
    floatx4 acc1 = {0.f, 0.f, 0.f, 0.f};
#pragma unroll
    for (int s = 0; s < 8; s++) {
        acc0 = __builtin_amdgcn_mfma_f32_16x16x32_f16(wf[0][s], buf[s], acc0, 0, 0, 0);
        acc1 = __builtin_amdgcn_mfma_f32_16x16x32_f16(wf[1][s], buf[s], acc1, 0, 0, 0);
    }
    int m = t * 16 + lm;
    if (m < n) {
        _Float16* crow = C + (size_t)m * DH + c0 + kg * 4;
        __half2 h0 = __float22half2_rn(make_float2(acc0[0], acc0[1]));
        __half2 h1 = __float22half2_rn(make_float2(acc0[2], acc0[3]));
        uint2 u;
        u.x = *(unsigned int*)&h0; u.y = *(unsigned int*)&h1;
        *(uint2*)crow = u;
        h0 = __float22half2_rn(make_float2(acc1[0], acc1[1]));
        h1 = __float22half2_rn(make_float2(acc1[2], acc1[3]));
        u.x = *(unsigned int*)&h0; u.y = *(unsigned int*)&h1;
        *(uint2*)(crow + 16) = u;
    }
}

__global__ __launch_bounds__(512, 2) void k_gemm_w(const _Float16* __restrict__ Xh,
                                                   const _Float16* __restrict__ Wt,
                                                   _Float16* __restrict__ C,
                                                   int n, int ntiles, int cpb) {
    int tid = threadIdx.x;
    int wave = tid >> 6, lane = tid & 63;
    int lm = lane & 15;
    int kg = lane >> 4;
    int c0 = wave * 32;

    half8 wfrag[2][8];
#pragma unroll
    for (int jj = 0; jj < 2; jj++)
#pragma unroll
        for (int s = 0; s < 8; s++)
            wfrag[jj][s] = *(const half8*)(Wt + (size_t)(c0 + jj * 16 + lm) * DH + s * 32 + kg * 8);

    int tstart = blockIdx.x * cpb;
    if (tstart >= ntiles) return;
    int tend = min(tstart + cpb, ntiles);

    half8 b0[8], b1[8], b2[8], b3[8];
    gload(b0, tstart,     tend, lm, kg, Xh, n);
    gload(b1, tstart + 1, tend, lm, kg, Xh, n);
    gload(b2, tstart + 2, tend, lm, kg, Xh, n);

    for (int t = tstart; t < tend; t += 4) {
        gload(b3, t + 3, tend, lm, kg, Xh, n);
        gcomp(b0, wfrag, t,     tend, lm, kg, c0, C, n);
        gload(b0, t + 4, tend, lm, kg, Xh, n);
        gcomp(b1, wfrag, t + 1, tend, lm, kg, c0, C, n);
        gload(b1, t + 5, tend, lm, kg, Xh, n);
        gcomp(b2, wfrag, t + 2, tend, lm, kg, c0, C, n);
        gload(b2, t + 6, tend, lm, kg, Xh, n);
        gcomp(b3, wfrag, t + 3, tend, lm, kg, c0, C, n);
    }
}

// ---------------------------------------------------------------- aggregation
// one WAVE per dst node; A is f16, 8B/lane; 8 gathers in flight, clamp+zero
// for the tail (extra gathers are L1 hits with w=0 -> numerically exact).

__device__ __forceinline__ float4 agg_core(const __half* __restrict__ A,
                                           const int* __restrict__ row_ptr,
                                           const int* __restrict__ col,
                                           const float* __restrict__ wgt,
                                           int node, int lane) {
    int p0 = row_ptr[node], p1 = row_ptr[node + 1];
    const __half* Al = A + lane * 4;
    float a0 = 0.f, a1 = 0.f, a2 = 0.f, a3 = 0.f;
    for (int p = p0; p < p1; p += 8) {
        int   cc[8];
        float w[8];
#pragma unroll
        for (int q = 0; q < 8; q++) {
            int idx = p + q;
            cc[q] = col[min(idx, p1 - 1)];
            w[q] = (idx < p1) ? wgt[idx] : 0.f;
        }
        uint2 u[8];
#pragma unroll
        for (int q = 0; q < 8; q++)
            u[q] = *(const uint2*)(Al + (size_t)cc[q] * DH);
#pragma unroll
        for (int q = 0; q < 8; q++) {
            float2 fa = __half22float2(*(__half2*)&u[q].x);
            float2 fb = __half22float2(*(__half2*)&u[q].y);
            a0 += w[q] * fa.x;
            a1 += w[q] * fa.y;
            a2 += w[q] * fb.x;
            a3 += w[q] * fb.y;
        }
    }
    return make_float4(a0, a1, a2, a3);
}

// variant 1: f16 output (h1, feeds gemm2)
__global__ __launch_bounds__(256) void k_agg_h(const __half* __restrict__ A,
                                               const int* __restrict__ row_ptr,
                                               const int* __restrict__ col,
                                               const float* __restrict__ wgt,
                                               const float* __restrict__ bias,
                                               __half* __restrict__ out, int n) {
    int node = (blockIdx.x << 2) + (threadIdx.x >> 6);
    int lane = threadIdx.x & 63;
    if (node >= n) return;
    node = __builtin_amdgcn_readfirstlane(node);
    float4 a = agg_core(A, row_ptr, col, wgt, node, lane);
    int f = lane * 4;
    float4 b4 = *(const float4*)&bias[f];
    __half2 h0 = __float22half2_rn(make_float2(fmaxf(a.x + b4.x, 0.f), fmaxf(a.y + b4.y, 0.f)));
    __half2 h1 = __float22half2_rn(make_float2(fmaxf(a.z + b4.z, 0.f), fmaxf(a.w + b4.w, 0.f)));
    uint2 u;
    u.x = *(unsigned int*)&h0;
    u.y = *(unsigned int*)&h1;
    *(uint2*)(out + (size_t)node * DH + f) = u;
}

// variant 2: f32 output (final h) + fused edge-predictor dot s[node]=h.We
__global__ __launch_bounds__(256) void k_agg_f(const __half* __restrict__ A,
                                               const int* __restrict__ row_ptr,
                                               const int* __restrict__ col,
                                               const float* __restrict__ wgt,
                                               const float* __restrict__ bias,
                                               const float* __restrict__ We,
                                               float* __restrict__ out,
                                               float* __restrict__ s, int n) {
    int node = (blockIdx.x << 2) + (threadIdx.x >> 6);
    int lane = threadIdx.x & 63;
    if (node >= n) return;
    node = __builtin_amdgcn_readfirstlane(node);
    float4 a = agg_core(A, row_ptr, col, wgt, node, lane);
    int f = lane * 4;
    float4 b4 = *(const float4*)&bias[f];
    float4 v = make_float4(fmaxf(a.x + b4.x, 0.f), fmaxf(a.y + b4.y, 0.f),
                           fmaxf(a.z + b4.z, 0.f), fmaxf(a.w + b4.w, 0.f));
    *(float4*)&out[(size_t)node * DH + f] = v;

    float4 wv = *(const float4*)&We[f];
    float d = v.x * wv.x + v.y * wv.y + v.z * wv.z + v.w * wv.w;
#pragma unroll
    for (int off = 32; off > 0; off >>= 1) d += __shfl_down(d, off);
    if (lane == 0) s[node] = d;
}

// ---------------------------------------------------------------- edge output

__global__ void k_y(const int* __restrict__ src, const int* __restrict__ dst,
                    const float* __restrict__ s, const float* __restrict__ be,
                    float* __restrict__ y, int e) {
    int i = blockIdx.x * blockDim.x + threadIdx.x;
    if (i < e) y[i] = 0.5f * (s[src[i]] + s[dst[i]]) + be[0];
}

// ---------------------------------------------------------------- launch

extern "C" void kernel_launch(void* const* d_in, const int* in_sizes, int n_in,
                              void* d_out, int out_size, void* d_ws, size_t ws_size,
                              hipStream_t stream) {
    const float* x  = (const float*)d_in[0];
    const int*   ei = (const int*)d_in[1];
    const float* W1 = (const float*)d_in[2];
    const float* b1 = (const float*)d_in[3];
    const float* W2 = (const float*)d_in[4];
    const float* b2 = (const float*)d_in[5];
    const float* We = (const float*)d_in[6];
    const float* be = (const float*)d_in[7];

    int n = in_sizes[0] / DH;
    int e = in_sizes[1] / 2;
    const int* src = ei;
    const int* dst = ei + e;

    float* out_h = (float*)d_out;                   // n*DH f32 (final)
    float* out_y = out_h + (size_t)n * DH;          // e
    // Xh (f16 cast of x) lives in the out_h region until agg_f overwrites it.
    _Float16* Xh = (_Float16*)d_out;

    char* w = (char*)d_ws;
    _Float16* A   = (_Float16*)w;  w += ((size_t)n * DH * 2 + 255) & ~255ull;
    _Float16* h1  = (_Float16*)w;  w += ((size_t)n * DH * 2 + 255) & ~255ull;
    _Float16* Wt1 = (_Float16*)w;  w += (size_t)DH * DH * 2;
    _Float16* Wt2 = (_Float16*)w;  w += (size_t)DH * DH * 2;
    float* deg    = (float*)w;  w += (size_t)n * 4;
    float* dinv   = (float*)w;  w += (size_t)n * 4;
    int*   row_ptr= (int*)w;    w += (size_t)(n + 1) * 4;
    int*   fill   = (int*)w;    w += (size_t)n * 4;
    int*   col    = (int*)w;    w += (size_t)(e + n + 8) * 4;   // +8 pad for clamp reads
    float* wgt    = (float*)w;  w += (size_t)(e + n + 8) * 4;   // +8 pad
    float* sbuf   = (float*)w;  w += (size_t)n * 4;
    int*   part   = (int*)w;    w += 4096;

    const int tb = 256;
    int nscan = (n + 1023) / 1024;
    k_init<<<(n + tb - 1) / tb, tb, 0, stream>>>(deg, fill, n);
    k_deg<<<(e + tb - 1) / tb, tb, 0, stream>>>(dst, deg, e);
    k_scan1<<<nscan, 1024, 0, stream>>>(deg, dinv, row_ptr, part, n);
    k_scan2<<<1, 64, 0, stream>>>(part, row_ptr, nscan, n);
    k_scan3<<<nscan, 1024, 0, stream>>>(row_ptr, part, dinv, col, wgt, fill, n);
    k_csr<<<(e + tb - 1) / tb, tb, 0, stream>>>(src, dst, dinv, row_ptr, fill, col, wgt, e);
    dim3 gt(8, 8, 2);
    k_tw<<<gt, 256, 0, stream>>>(W1, Wt1, W2, Wt2);
    k_xh<<<2048, 256, 0, stream>>>(x, Xh, (n * DH) / 8);

    int ntiles = (n + 15) / 16;
    int cpb = (ntiles + 255) / 256;
    k_gemm_w<<<256, 512, 0, stream>>>(Xh, Wt1, A, n, ntiles, cpb);              // A = x@W1
    k_agg_h<<<(n + 3) / 4, 256, 0, stream>>>((const __half*)A, row_ptr, col, wgt, b1,
                                             (__half*)h1, n);                   // h1 (f16)
    k_gemm_w<<<256, 512, 0, stream>>>(h1, Wt2, A, n, ntiles, cpb);              // A = h1@W2
    k_agg_f<<<(n + 3) / 4, 256, 0, stream>>>((const __half*)A, row_ptr, col, wgt, b2,
                                             We, out_h, sbuf, n);               // final h + s
    k_y<<<(e + tb - 1) / tb, tb, 0, stream>>>(src, dst, sbuf, be, out_y, e);
}